// Round 5
// baseline (726.497 us; speedup 1.0000x reference)
//
#include <hip/hip_runtime.h>
#include <hip/hip_cooperative_groups.h>

namespace cg = cooperative_groups;

#define DEVI __device__ __forceinline__

constexpr float SCALE = 0.0625f;   // 256^-0.5
constexpr float LN_EPS = 1e-5f;

// ---------- helpers for the once-only k_initq (proven, unchanged) ----------
DEVI float gemv_row(const float* __restrict__ W, const float4* __restrict__ xv4, int tid){
  const float4* wr = (const float4*)(W + (size_t)tid*256);
  float a0=0.f, a1=0.f, a2=0.f, a3=0.f;
  #pragma unroll 16
  for (int k = 0; k < 64; ++k){
    float4 w = wr[k];
    float4 x = xv4[k];
    a0 += w.x*x.x; a1 += w.y*x.y; a2 += w.z*x.z; a3 += w.w*x.w;
  }
  return (a0+a1)+(a2+a3);
}

DEVI float gemv_col(const float* __restrict__ W, const float4* __restrict__ xv4, int tid){
  const float* wc = W + tid;
  float a0=0.f, a1=0.f, a2=0.f, a3=0.f;
  #pragma unroll 8
  for (int e4 = 0; e4 < 64; ++e4){
    float4 x = xv4[e4];
    const float* p = wc + (size_t)e4*1024;
    a0 += x.x*p[0]; a1 += x.y*p[256]; a2 += x.z*p[512]; a3 += x.w*p[768];
  }
  return (a0+a1)+(a2+a3);
}

DEVI float block_ln(float x, const float* __restrict__ g, const float* __restrict__ be,
                    float* red, int tid, int lane, int wv){
  float v1 = x, v2 = x*x;
  #pragma unroll
  for (int o = 32; o; o >>= 1){ v1 += __shfl_xor(v1,o,64); v2 += __shfl_xor(v2,o,64); }
  if (lane == 0){ red[wv] = v1; red[4+wv] = v2; }
  __syncthreads();
  float mu = (red[0]+red[1]+red[2]+red[3]) * (1.f/256.f);
  float var = (red[4]+red[5]+red[6]+red[7]) * (1.f/256.f) - mu*mu;
  float inv = rsqrtf(var + LN_EPS);
  float r = (x - mu)*inv*g[tid] + be[tid];
  __syncthreads();
  return r;
}

DEVI void qproj(float sval, int r, int s, int tid,
                const float* __restrict__ g_s, const float* __restrict__ be_s,
                const float* __restrict__ Wq, const float* __restrict__ Wk,
                const float* __restrict__ g_in, const float* __restrict__ be_in,
                float* __restrict__ qg, float* __restrict__ gqbq,
                float4* xv4, float* red){
  float* xv = (float*)xv4;
  const int lane = tid & 63, wv = tid >> 6;
  float sn = block_ln(sval, g_s, be_s, red, tid, lane, wv);
  xv[tid] = sn;
  __syncthreads();
  float q = gemv_row(Wq, xv4, tid);
  __syncthreads();
  xv[tid] = q;
  __syncthreads();
  float qk = gemv_col(Wk + (size_t)s*65536, xv4, tid);
  float qgv = qk * g_in[tid] * SCALE;
  float bqv = qk * be_in[tid] * SCALE;
  qg[r*256 + tid] = qgv;
  float vq = qgv, vb = bqv;
  #pragma unroll
  for (int o = 32; o; o >>= 1){ vq += __shfl_xor(vq,o,64); vb += __shfl_xor(vb,o,64); }
  if (lane == 0){ red[wv] = vq; red[4+wv] = vb; }
  __syncthreads();
  if (tid == 0) gqbq[r*2+0] = red[0]+red[1]+red[2]+red[3];
  if (tid == 1) gqbq[r*2+1] = red[4]+red[5]+red[6]+red[7];
}

// ---------------- kInitQ: slots init + zero accumulators + q-projection (once) ---------
__global__ __launch_bounds__(256) void k_initq(const float* __restrict__ noise,
    const float* __restrict__ smu, const float* __restrict__ slsig,
    float* __restrict__ slotsA, float* __restrict__ uacc, float* __restrict__ Zacc,
    const float* __restrict__ g_s, const float* __restrict__ be_s,
    const float* __restrict__ Wq, const float* __restrict__ Wk,
    const float* __restrict__ g_in, const float* __restrict__ be_in,
    float* __restrict__ qg, float* __restrict__ gqbq){
  __shared__ float4 xv4[64];
  __shared__ float red[8];
  const int r = blockIdx.x, tid = threadIdx.x, s = r & 7;
  float sl = smu[s*256 + tid] + expf(slsig[s*256 + tid]) * noise[r*256 + tid];
  slotsA[r*256 + tid] = sl;
  uacc[r*256 + tid] = 0.f;
  if (tid == 0) Zacc[r] = 0.f;
  qproj(sl, r, s, tid, g_s, be_s, Wq, Wk, g_in, be_in, qg, gqbq, xv4, red);
}

// ---------------- cooperative fused slot-update ----------------
// 256 blocks (all CUs). Rows grouped by slot: r = sg + 8*j, j=0..15.
// Phases (grid.sync between): A: upd=(uacc@Wv[s]^T)/Z, gh=sin@W_hh^T+b_hh
//   B: gi=upd@W_ih^T+b_ih, GRU -> hbuf; zero uacc/Zacc
//   C: LN_ff -> W1 -> relu -> hid     D: sout = hbuf + hid@W2^T + b2
//   E: LN_s -> Wq -> qbuf; zero gqbq  F: qk=q@Wk[s], qg, Gq/Bq atomics
struct UpdP {
  const float *sin_; float *sout;
  float *uacc, *Zacc;
  const float *Wv, *W_ih, *W_hh, *b_ih, *b_hh;
  const float *g_ff, *be_ff, *W1, *b1, *W2, *b2;
  const float *g_s, *be_s, *Wq, *Wk, *g_in, *be_in;
  float *qg, *gqbq;
  float *upd, *gh, *hbuf, *hid, *qbuf;
  float *out_slots; int last;
};

DEVI float dot256(const float* w, const float* x){
  float4 A = make_float4(0.f,0.f,0.f,0.f);
  #pragma unroll 8
  for (int k = 0; k < 64; ++k){
    float4 w4 = *(const float4*)(w + k*4);
    float4 x4 = *(const float4*)(x + k*4);
    A.x += w4.x*x4.x; A.y += w4.y*x4.y; A.z += w4.z*x4.z; A.w += w4.w*x4.w;
  }
  return (A.x+A.y)+(A.z+A.w);
}

__global__ __launch_bounds__(256) void k_upd_coop(UpdP P){
  cg::grid_group grid = cg::this_grid();
  __shared__ float xs[16][260];     // x rows (stride 1040B: b128 conflict-free)
  __shared__ float ws[32][260];     // weight rows / columns
  __shared__ float gA[256], gB[256];
  __shared__ float redA[16][17], redB[16][17];
  __shared__ float musL[16], invsL[16];
  const int tid = threadIdx.x, bid = blockIdx.x;

  // ================= phase A =================
  {
    const int m = bid >> 6, sg = (bid >> 3) & 7, cgi = bid & 7, cbase = cgi * 32;
    const float* W = (m == 0) ? (P.Wv + (size_t)sg*65536) : (P.W_hh + (size_t)(m-1)*65536);
    const float* xsrc = (m == 0) ? P.uacc : P.sin_;
    #pragma unroll
    for (int i = 0; i < 4; ++i){
      int idx4 = tid + i*256, j = idx4 >> 6, k4 = idx4 & 63;
      *(float4*)&xs[j][k4*4] = *(const float4*)(xsrc + ((size_t)(sg + 8*j))*256 + k4*4);
    }
    #pragma unroll
    for (int i = 0; i < 8; ++i){
      int idx4 = tid + i*256, row = idx4 >> 6, k4 = idx4 & 63;
      *(float4*)&ws[row][k4*4] = *(const float4*)(W + ((size_t)(cbase + row))*256 + k4*4);
    }
    __syncthreads();
    const int j0 = tid >> 5, cc = tid & 31, c = cbase + cc;
    float4 A0 = make_float4(0.f,0.f,0.f,0.f), A1 = make_float4(0.f,0.f,0.f,0.f);
    #pragma unroll 8
    for (int k = 0; k < 64; ++k){
      float4 w4 = *(const float4*)&ws[cc][k*4];
      float4 x0 = *(const float4*)&xs[j0][k*4];
      float4 x1 = *(const float4*)&xs[j0+8][k*4];
      A0.x += w4.x*x0.x; A0.y += w4.y*x0.y; A0.z += w4.z*x0.z; A0.w += w4.w*x0.w;
      A1.x += w4.x*x1.x; A1.y += w4.y*x1.y; A1.z += w4.z*x1.z; A1.w += w4.w*x1.w;
    }
    float d0 = (A0.x+A0.y)+(A0.z+A0.w);
    float d1 = (A1.x+A1.y)+(A1.z+A1.w);
    const int r0 = sg + 8*j0, r1 = sg + 8*(j0+8);
    if (m == 0){
      P.upd[(size_t)r0*256 + c] = d0 / P.Zacc[r0];
      P.upd[(size_t)r1*256 + c] = d1 / P.Zacc[r1];
    } else {
      int g = m-1;
      float bh = P.b_hh[g*256 + c];
      P.gh[((size_t)g*128 + r0)*256 + c] = d0 + bh;
      P.gh[((size_t)g*128 + r1)*256 + c] = d1 + bh;
    }
  }
  grid.sync();

  const int sg = bid >> 5, cgi = bid & 31, cbase = cgi * 8;
  const int j = tid >> 3, cc = tid & 7;         // active mapping (tid<128)
  const int r = sg + 8*j, c = cbase + cc;

  // ================= phase B =================
  {
    #pragma unroll
    for (int i = 0; i < 4; ++i){
      int idx4 = tid + i*256, jj = idx4 >> 6, k4 = idx4 & 63;
      *(float4*)&xs[jj][k4*4] = *(const float4*)(P.upd + ((size_t)(sg + 8*jj))*256 + k4*4);
    }
    #pragma unroll
    for (int i = 0; i < 6; ++i){
      int idx4 = tid + i*256, row = idx4 >> 6, k4 = idx4 & 63;
      int g = row >> 3, rr = row & 7;
      *(float4*)&ws[row][k4*4] =
        *(const float4*)(P.W_ih + (size_t)g*65536 + ((size_t)(cbase + rr))*256 + k4*4);
    }
    __syncthreads();
    if (tid < 128){
      float ir_ = dot256(&ws[cc][0],    &xs[j][0]) + P.b_ih[c];
      float iz_ = dot256(&ws[8+cc][0],  &xs[j][0]) + P.b_ih[256 + c];
      float in_ = dot256(&ws[16+cc][0], &xs[j][0]) + P.b_ih[512 + c];
      float hr_ = P.gh[((size_t)0*128 + r)*256 + c];
      float hz_ = P.gh[((size_t)1*128 + r)*256 + c];
      float hn_ = P.gh[((size_t)2*128 + r)*256 + c];
      float hp  = P.sin_[(size_t)r*256 + c];
      float rg = 1.f/(1.f + expf(-(ir_ + hr_)));
      float zg = 1.f/(1.f + expf(-(iz_ + hz_)));
      float ng = tanhf(in_ + rg*hn_);
      P.hbuf[(size_t)r*256 + c] = (1.f - zg)*ng + zg*hp;
      P.uacc[(size_t)r*256 + c] = 0.f;            // covered exactly once
    }
    if (cgi == 0 && tid < 16) P.Zacc[sg + 8*tid] = 0.f;
  }
  grid.sync();

  // ================= phase C =================
  {
    #pragma unroll
    for (int i = 0; i < 4; ++i){
      int idx4 = tid + i*256, jj = idx4 >> 6, k4 = idx4 & 63;
      *(float4*)&xs[jj][k4*4] = *(const float4*)(P.hbuf + ((size_t)(sg + 8*jj))*256 + k4*4);
    }
    #pragma unroll
    for (int i = 0; i < 2; ++i){
      int idx4 = tid + i*256, row = idx4 >> 6, k4 = idx4 & 63;
      *(float4*)&ws[row][k4*4] = *(const float4*)(P.W1 + ((size_t)(cbase + row))*256 + k4*4);
    }
    gA[tid] = P.g_ff[tid]; gB[tid] = P.be_ff[tid];
    __syncthreads();
    { // per-row LN stats + in-place transform
      int jr = tid >> 4, seg = tid & 15;
      float s1 = 0.f, s2 = 0.f;
      #pragma unroll
      for (int i = 0; i < 16; ++i){ float v = xs[jr][seg*16 + i]; s1 += v; s2 += v*v; }
      redA[jr][seg] = s1; redB[jr][seg] = s2;
      __syncthreads();
      if (tid < 16){
        float t1 = 0.f, t2 = 0.f;
        #pragma unroll
        for (int p = 0; p < 16; ++p){ t1 += redA[tid][p]; t2 += redB[tid][p]; }
        float mu = t1 * (1.f/256.f);
        float var = t2 * (1.f/256.f) - mu*mu;
        musL[tid] = mu; invsL[tid] = rsqrtf(var + LN_EPS);
      }
      __syncthreads();
      float mu = musL[jr], inv = invsL[jr];
      #pragma unroll
      for (int i = 0; i < 16; ++i){
        int k = seg*16 + i;
        xs[jr][k] = (xs[jr][k] - mu)*inv*gA[k] + gB[k];
      }
    }
    __syncthreads();
    if (tid < 128)
      P.hid[(size_t)r*256 + c] = fmaxf(dot256(&ws[cc][0], &xs[j][0]) + P.b1[c], 0.f);
  }
  grid.sync();

  // ================= phase D =================
  {
    #pragma unroll
    for (int i = 0; i < 4; ++i){
      int idx4 = tid + i*256, jj = idx4 >> 6, k4 = idx4 & 63;
      *(float4*)&xs[jj][k4*4] = *(const float4*)(P.hid + ((size_t)(sg + 8*jj))*256 + k4*4);
    }
    #pragma unroll
    for (int i = 0; i < 2; ++i){
      int idx4 = tid + i*256, row = idx4 >> 6, k4 = idx4 & 63;
      *(float4*)&ws[row][k4*4] = *(const float4*)(P.W2 + ((size_t)(cbase + row))*256 + k4*4);
    }
    __syncthreads();
    if (tid < 128){
      float out = P.hbuf[(size_t)r*256 + c] + dot256(&ws[cc][0], &xs[j][0]) + P.b2[c];
      P.sout[(size_t)r*256 + c] = out;
      if (P.last) P.out_slots[(size_t)r*256 + c] = out;
    }
  }
  if (P.last) return;                 // uniform across the whole grid
  grid.sync();

  // ================= phase E =================
  {
    #pragma unroll
    for (int i = 0; i < 4; ++i){
      int idx4 = tid + i*256, jj = idx4 >> 6, k4 = idx4 & 63;
      *(float4*)&xs[jj][k4*4] = *(const float4*)(P.sout + ((size_t)(sg + 8*jj))*256 + k4*4);
    }
    #pragma unroll
    for (int i = 0; i < 2; ++i){
      int idx4 = tid + i*256, row = idx4 >> 6, k4 = idx4 & 63;
      *(float4*)&ws[row][k4*4] = *(const float4*)(P.Wq + ((size_t)(cbase + row))*256 + k4*4);
    }
    gA[tid] = P.g_s[tid]; gB[tid] = P.be_s[tid];
    __syncthreads();
    {
      int jr = tid >> 4, seg = tid & 15;
      float s1 = 0.f, s2 = 0.f;
      #pragma unroll
      for (int i = 0; i < 16; ++i){ float v = xs[jr][seg*16 + i]; s1 += v; s2 += v*v; }
      redA[jr][seg] = s1; redB[jr][seg] = s2;
      __syncthreads();
      if (tid < 16){
        float t1 = 0.f, t2 = 0.f;
        #pragma unroll
        for (int p = 0; p < 16; ++p){ t1 += redA[tid][p]; t2 += redB[tid][p]; }
        float mu = t1 * (1.f/256.f);
        float var = t2 * (1.f/256.f) - mu*mu;
        musL[tid] = mu; invsL[tid] = rsqrtf(var + LN_EPS);
      }
      __syncthreads();
      float mu = musL[jr], inv = invsL[jr];
      #pragma unroll
      for (int i = 0; i < 16; ++i){
        int k = seg*16 + i;
        xs[jr][k] = (xs[jr][k] - mu)*inv*gA[k] + gB[k];
      }
    }
    __syncthreads();
    if (tid < 128)
      P.qbuf[(size_t)r*256 + c] = dot256(&ws[cc][0], &xs[j][0]);
    if (cgi == 0 && tid < 32)
      P.gqbq[(sg + 8*(tid>>1))*2 + (tid&1)] = 0.f;
  }
  grid.sync();

  // ================= phase F =================
  {
    const int s = sg;                  // rows sg+8j all have slot sg
    #pragma unroll
    for (int i = 0; i < 4; ++i){
      int idx4 = tid + i*256, jj = idx4 >> 6, k4 = idx4 & 63;
      *(float4*)&xs[jj][k4*4] = *(const float4*)(P.qbuf + ((size_t)(sg + 8*jj))*256 + k4*4);
    }
    #pragma unroll
    for (int i = 0; i < 8; ++i){       // gather 8 columns of Wk[s]
      int idx = tid + i*256;
      int cl = idx & 7, e = idx >> 3;
      ws[cl][e] = P.Wk[(size_t)s*65536 + (size_t)e*256 + cbase + cl];
    }
    __syncthreads();
    if (tid < 128){
      float qk = dot256(&ws[cc][0], &xs[j][0]);
      float qgv = qk * P.g_in[c] * SCALE;
      float bqv = qk * P.be_in[c] * SCALE;
      P.qg[(size_t)r*256 + c] = qgv;
      float vq = qgv, vb = bqv;
      #pragma unroll
      for (int o = 1; o <= 4; o <<= 1){ vq += __shfl_xor(vq,o,64); vb += __shfl_xor(vb,o,64); }
      if (cc == 0){
        atomicAdd(&P.gqbq[r*2+0], vq);
        atomicAdd(&P.gqbq[r*2+1], vb);
      }
    }
  }
}

// ---------------- K1: fused LN + dots + softmax(slots) + weighted-emb accumulation ------
__global__ __launch_bounds__(256) void k_main(const float* __restrict__ emb,
    const float* __restrict__ qg, const float* __restrict__ gqbq,
    const float* __restrict__ g_in, const float* __restrict__ be_in,
    float* __restrict__ uacc, float* __restrict__ Zacc,
    float* __restrict__ out_attn, int write_attn){
  __shared__ float U[8192];                    // 32 KB union
  float* const qgL = U;                        // [2048] phase 1 (bank-swizzled)
  float* const avL = U + 2048;                 // [512]  phase 1
  float4* const Sp4 = (float4*)U;              // [2048] phase 2 partials
  __shared__ float aL[512];
  __shared__ float red2[2][8][4];
  __shared__ float Zs[8], A2s[8], GqL[8], BqL[8];

  const int tid = threadIdx.x, lane = tid & 63, wv = tid >> 6;
  const int blk = blockIdx.x, b = blk >> 6, tile = blk & 63;
  const int n0 = tile * 64;

  { // stage queries with per-qq rotation so the 8 qq-chunks hit distinct banks
    const float4* src = (const float4*)(qg + (size_t)b * 2048);
    float4* dst = (float4*)qgL;
    #pragma unroll
    for (int k = 0; k < 2; ++k){
      int w = tid + k*256;                 // 0..511
      int s = w >> 6, f = w & 63, qq = f >> 3, j = f & 7;
      dst[s*64 + qq*8 + ((j + qq) & 7)] = src[w];
    }
  }
  if (tid < 8){
    GqL[tid] = gqbq[(b*8 + tid)*2 + 0];
    BqL[tid] = gqbq[(b*8 + tid)*2 + 1];
  }
  __syncthreads();

  const int qq = tid & 7;   // 32-col chunk
  float zsum[8], z2sum[8];
  #pragma unroll
  for (int s = 0; s < 8; ++s){ zsum[s] = 0.f; z2sum[s] = 0.f; }

  #pragma unroll
  for (int pass = 0; pass < 2; ++pass){
    const int t = pass*32 + (tid >> 3);   // token 0..63
    const float4* xrow = (const float4*)(emb + ((size_t)(b*4096 + n0 + t))*256 + qq*32);
    float4 xv4[8];
    #pragma unroll
    for (int j = 0; j < 8; ++j) xv4[j] = xrow[j];
    float s1 = 0.f, s2 = 0.f, acc[8];
    #pragma unroll
    for (int s = 0; s < 8; ++s) acc[s] = 0.f;
    #pragma unroll
    for (int j = 0; j < 8; ++j){
      float4 u = xv4[j];
      s1 += (u.x+u.y)+(u.z+u.w);
      s2 += u.x*u.x+u.y*u.y+u.z*u.z+u.w*u.w;
      const float* qb = qgL + qq*32 + ((j + qq) & 7)*4;
      #pragma unroll
      for (int s = 0; s < 8; ++s){
        float4 q0 = *(const float4*)(qb + s*256);
        acc[s] += u.x*q0.x + u.y*q0.y + u.z*q0.z + u.w*q0.w;
      }
    }
    #pragma unroll
    for (int o = 1; o <= 4; o <<= 1){
      s1 += __shfl_xor(s1,o,64); s2 += __shfl_xor(s2,o,64);
      #pragma unroll
      for (int s = 0; s < 8; ++s) acc[s] += __shfl_xor(acc[s],o,64);
    }
    float mu = s1 * (1.f/256.f);
    float var = s2 * (1.f/256.f) - mu*mu;
    float inv = rsqrtf(var + LN_EPS);
    float dv[8], mx = -1e30f;
    #pragma unroll
    for (int s = 0; s < 8; ++s){
      dv[s] = inv * (acc[s] - mu * GqL[s]) + BqL[s];
      mx = fmaxf(mx, dv[s]);
    }
    float den = 0.f;
    #pragma unroll
    for (int s = 0; s < 8; ++s){ dv[s] = expf(dv[s] - mx); den += dv[s]; }
    float rden = 1.f / den;
    #pragma unroll
    for (int s = 0; s < 8; ++s){
      float at = dv[s] * rden;       // attn (softmax over slots)
      float av = at * inv;           // attn * inv (LN folded)
      if (qq == 0){ avL[s*64 + t] = at; aL[s*64 + t] = av; }
      zsum[s] += at;
      z2sum[s] += av * mu;
    }
  }
  #pragma unroll
  for (int s = 0; s < 8; ++s){
    #pragma unroll
    for (int o = 32; o; o >>= 1){
      zsum[s] += __shfl_xor(zsum[s], o, 64);
      z2sum[s] += __shfl_xor(z2sum[s], o, 64);
    }
  }
  if (lane == 0){
    #pragma unroll
    for (int s = 0; s < 8; ++s){ red2[0][s][wv] = zsum[s]*0.125f; red2[1][s][wv] = z2sum[s]*0.125f; }
  }
  __syncthreads();
  if (tid < 8){
    Zs[tid]  = red2[0][tid][0]+red2[0][tid][1]+red2[0][tid][2]+red2[0][tid][3];
    A2s[tid] = red2[1][tid][0]+red2[1][tid][1]+red2[1][tid][2]+red2[1][tid][3];
  }
  if (write_attn){
    int s = tid >> 5, tk = tid & 31;
    #pragma unroll
    for (int p = 0; p < 2; ++p)
      out_attn[((size_t)(b*8 + s))*4096 + n0 + p*32 + tk] = avL[s*64 + p*32 + tk];
  }
  __syncthreads();                   // avL/qgL dead past here; Sp4 takes over U
  { // phase 2: coalesced f4 token-weighted accumulation
    const int r4 = tid >> 6, cq = tid & 63;
    float4 S1[8];
    #pragma unroll
    for (int s = 0; s < 8; ++s) S1[s] = make_float4(0.f,0.f,0.f,0.f);
    const float4* xbase = (const float4*)(emb + ((size_t)(b*4096 + n0))*256) + cq;
    #pragma unroll 4
    for (int i = 0; i < 16; ++i){
      int t = r4 + i*4;
      float4 x4 = xbase[t*64];
      #pragma unroll
      for (int s = 0; s < 8; ++s){
        float a = aL[s*64 + t];
        S1[s].x += a*x4.x; S1[s].y += a*x4.y; S1[s].z += a*x4.z; S1[s].w += a*x4.w;
      }
    }
    #pragma unroll
    for (int s = 0; s < 8; ++s) Sp4[(r4*8 + s)*64 + cq] = S1[s];
  }
  __syncthreads();
  { // final: sum 4 wave-partials per (s,c), atomically accumulate (s staggered)
    const int c = tid;
    const float* Sp = (const float*)Sp4;
    float gc = g_in[c], bc = be_in[c];
    float* dst = uacc + ((size_t)b*8)*256 + c;
    #pragma unroll
    for (int si = 0; si < 8; ++si){
      int s = (si + blk) & 7;
      float v = Sp[(0*8+s)*256 + c] + Sp[(1*8+s)*256 + c]
              + Sp[(2*8+s)*256 + c] + Sp[(3*8+s)*256 + c];
      atomicAdd(&dst[s*256], gc * (v - A2s[s]) + bc * Zs[s]);
    }
    if (tid < 8) atomicAdd(&Zacc[b*8 + tid], Zs[tid]);
  }
}

extern "C" void kernel_launch(void* const* d_in, const int* in_sizes, int n_in,
                              void* d_out, int out_size, void* d_ws, size_t ws_size,
                              hipStream_t stream){
  const float* emb   = (const float*)d_in[0];
  const float* noise = (const float*)d_in[1];
  const float* smu   = (const float*)d_in[2];
  const float* slsig = (const float*)d_in[3];
  const float* Wk    = (const float*)d_in[4];
  const float* Wq    = (const float*)d_in[5];
  const float* Wv    = (const float*)d_in[6];
  const float* W_ih  = (const float*)d_in[7];
  const float* W_hh  = (const float*)d_in[8];
  const float* b_ih  = (const float*)d_in[9];
  const float* b_hh  = (const float*)d_in[10];
  const float* W1    = (const float*)d_in[11];
  const float* b1    = (const float*)d_in[12];
  const float* W2    = (const float*)d_in[13];
  const float* b2    = (const float*)d_in[14];
  const float* g_in  = (const float*)d_in[15];
  const float* be_in = (const float*)d_in[16];
  const float* g_s   = (const float*)d_in[17];
  const float* be_s  = (const float*)d_in[18];
  const float* g_ff  = (const float*)d_in[19];
  const float* be_ff = (const float*)d_in[20];

  float* ws     = (float*)d_ws;
  float* slotsA = ws;                 // 32768
  float* slotsB = ws + 32768;         // 32768
  float* qg     = ws + 65536;         // 32768
  float* gqbq   = ws + 98304;         // 256
  float* uacc   = ws + 98560;         // 32768
  float* Zacc   = ws + 131328;        // 128
  float* updb   = ws + 131456;        // 32768
  float* ghb    = ws + 164224;        // 98304
  float* hbuf   = ws + 262528;        // 32768
  float* hid    = ws + 295296;        // 32768
  float* qbuf   = ws + 328064;        // 32768  (total ~1.44 MB)

  float* out_slots = (float*)d_out;
  float* out_attn  = out_slots + 32768;
  const int has_attn = (out_size >= 32768 + 16*8*4096);

  k_initq<<<dim3(128), dim3(256), 0, stream>>>(noise, smu, slsig, slotsA, uacc, Zacc,
      g_s, be_s, Wq, Wk, g_in, be_in, qg, gqbq);
  for (int it = 0; it < 3; ++it){
    int last = (it == 2);
    float* sin  = (it == 1) ? slotsB : slotsA;
    float* sout = (it == 1) ? slotsA : slotsB;
    k_main<<<dim3(1024), dim3(256), 0, stream>>>(emb, qg, gqbq, g_in, be_in,
        uacc, Zacc, out_attn, last && has_attn);
    UpdP P = { sin, sout, uacc, Zacc,
               Wv, W_ih, W_hh, b_ih, b_hh,
               g_ff, be_ff, W1, b1, W2, b2,
               g_s, be_s, Wq, Wk, g_in, be_in,
               qg, gqbq, updb, ghb, hbuf, hid, qbuf,
               out_slots, last };
    void* kargs[] = { (void*)&P };
    hipLaunchCooperativeKernel(k_upd_coop, dim3(256), dim3(256), kargs, 0u, stream);
  }
}

// Round 6
// 326.816 us; speedup vs baseline: 2.2230x; 2.2230x over previous
//
#include <hip/hip_runtime.h>

#define DEVI __device__ __forceinline__

constexpr float SCALE = 0.0625f;   // 256^-0.5
constexpr float LN_EPS = 1e-5f;

DEVI float dot256(const float* w, const float* x){
  float4 A = make_float4(0.f,0.f,0.f,0.f);
  #pragma unroll 8
  for (int k = 0; k < 64; ++k){
    float4 w4 = *(const float4*)(w + k*4);
    float4 x4 = *(const float4*)(x + k*4);
    A.x += w4.x*x4.x; A.y += w4.y*x4.y; A.z += w4.z*x4.z; A.w += w4.w*x4.w;
  }
  return (A.x+A.y)+(A.z+A.w);
}

// ---------- helpers for the once-only k_initq (proven rounds 4-5) ----------
DEVI float gemv_row(const float* __restrict__ W, const float4* __restrict__ xv4, int tid){
  const float4* wr = (const float4*)(W + (size_t)tid*256);
  float a0=0.f, a1=0.f, a2=0.f, a3=0.f;
  #pragma unroll 16
  for (int k = 0; k < 64; ++k){
    float4 w = wr[k];
    float4 x = xv4[k];
    a0 += w.x*x.x; a1 += w.y*x.y; a2 += w.z*x.z; a3 += w.w*x.w;
  }
  return (a0+a1)+(a2+a3);
}

DEVI float gemv_col(const float* __restrict__ W, const float4* __restrict__ xv4, int tid){
  const float* wc = W + tid;
  float a0=0.f, a1=0.f, a2=0.f, a3=0.f;
  #pragma unroll 8
  for (int e4 = 0; e4 < 64; ++e4){
    float4 x = xv4[e4];
    const float* p = wc + (size_t)e4*1024;
    a0 += x.x*p[0]; a1 += x.y*p[256]; a2 += x.z*p[512]; a3 += x.w*p[768];
  }
  return (a0+a1)+(a2+a3);
}

DEVI float block_ln(float x, const float* __restrict__ g, const float* __restrict__ be,
                    float* red, int tid, int lane, int wv){
  float v1 = x, v2 = x*x;
  #pragma unroll
  for (int o = 32; o; o >>= 1){ v1 += __shfl_xor(v1,o,64); v2 += __shfl_xor(v2,o,64); }
  if (lane == 0){ red[wv] = v1; red[4+wv] = v2; }
  __syncthreads();
  float mu = (red[0]+red[1]+red[2]+red[3]) * (1.f/256.f);
  float var = (red[4]+red[5]+red[6]+red[7]) * (1.f/256.f) - mu*mu;
  float inv = rsqrtf(var + LN_EPS);
  float r = (x - mu)*inv*g[tid] + be[tid];
  __syncthreads();
  return r;
}

DEVI void qproj(float sval, int r, int s, int tid,
                const float* __restrict__ g_s, const float* __restrict__ be_s,
                const float* __restrict__ Wq, const float* __restrict__ Wk,
                const float* __restrict__ g_in, const float* __restrict__ be_in,
                float* __restrict__ qg, float* __restrict__ gqbq,
                float4* xv4, float* red){
  float* xv = (float*)xv4;
  const int lane = tid & 63, wv = tid >> 6;
  float sn = block_ln(sval, g_s, be_s, red, tid, lane, wv);
  xv[tid] = sn;
  __syncthreads();
  float q = gemv_row(Wq, xv4, tid);
  __syncthreads();
  xv[tid] = q;
  __syncthreads();
  float qk = gemv_col(Wk + (size_t)s*65536, xv4, tid);
  float qgv = qk * g_in[tid] * SCALE;
  float bqv = qk * be_in[tid] * SCALE;
  qg[r*256 + tid] = qgv;
  float vq = qgv, vb = bqv;
  #pragma unroll
  for (int o = 32; o; o >>= 1){ vq += __shfl_xor(vq,o,64); vb += __shfl_xor(vb,o,64); }
  if (lane == 0){ red[wv] = vq; red[4+wv] = vb; }
  __syncthreads();
  if (tid == 0) gqbq[r*2+0] = red[0]+red[1]+red[2]+red[3];
  if (tid == 1) gqbq[r*2+1] = red[4]+red[5]+red[6]+red[7];
}

// ---------------- kInitQ: slots init + zero accumulators + q-projection (once) ---------
__global__ __launch_bounds__(256) void k_initq(const float* __restrict__ noise,
    const float* __restrict__ smu, const float* __restrict__ slsig,
    float* __restrict__ slotsA, float* __restrict__ uacc, float* __restrict__ Zacc,
    const float* __restrict__ g_s, const float* __restrict__ be_s,
    const float* __restrict__ Wq, const float* __restrict__ Wk,
    const float* __restrict__ g_in, const float* __restrict__ be_in,
    float* __restrict__ qg, float* __restrict__ gqbq){
  __shared__ float4 xv4[64];
  __shared__ float red[8];
  const int r = blockIdx.x, tid = threadIdx.x, s = r & 7;
  float sl = smu[s*256 + tid] + expf(slsig[s*256 + tid]) * noise[r*256 + tid];
  slotsA[r*256 + tid] = sl;
  uacc[r*256 + tid] = 0.f;
  if (tid == 0) Zacc[r] = 0.f;
  qproj(sl, r, s, tid, g_s, be_s, Wq, Wk, g_in, be_in, qg, gqbq, xv4, red);
}

// ===== tiled slot-update stage kernels (round-5 phase bodies, stream-ordered) =====
// All: 256 blocks = 8 slot-groups (sg) x 32 col-groups (cgi of 8 cols).
// Rows of slot-group sg: r = sg + 8*j, j = 0..15  (slot = r&7 = sg, batch = r>>3 = j).

// D2: upd[r][c] = dot(Wv[sg][c][:], uacc[r][:]) / Zacc[r]
__global__ __launch_bounds__(256) void k_updv(const float* __restrict__ uacc,
    const float* __restrict__ Zacc, const float* __restrict__ Wv,
    float* __restrict__ updb){
  __shared__ float xs[16][260];
  __shared__ float ws[8][260];
  const int tid = threadIdx.x, bid = blockIdx.x;
  const int sg = bid >> 5, cgi = bid & 31, cbase = cgi * 8;
  #pragma unroll
  for (int i = 0; i < 4; ++i){
    int idx4 = tid + i*256, jj = idx4 >> 6, k4 = idx4 & 63;
    *(float4*)&xs[jj][k4*4] = *(const float4*)(uacc + ((size_t)(sg + 8*jj))*256 + k4*4);
  }
  #pragma unroll
  for (int i = 0; i < 2; ++i){
    int idx4 = tid + i*256, row = idx4 >> 6, k4 = idx4 & 63;
    *(float4*)&ws[row][k4*4] =
      *(const float4*)(Wv + (size_t)sg*65536 + ((size_t)(cbase + row))*256 + k4*4);
  }
  __syncthreads();
  if (tid < 128){
    const int j = tid >> 3, cc = tid & 7, r = sg + 8*j, c = cbase + cc;
    updb[(size_t)r*256 + c] = dot256(&ws[cc][0], &xs[j][0]) / Zacc[r];
  }
}

// D3: gi gates + GRU -> hbuf; zero uacc/Zacc for next k_main
__global__ __launch_bounds__(256) void k_gru(const float* __restrict__ sin_,
    const float* __restrict__ updb, const float* __restrict__ ghb,
    const float* __restrict__ W_ih, const float* __restrict__ b_ih,
    float* __restrict__ hbuf, float* __restrict__ uacc, float* __restrict__ Zacc){
  __shared__ float xs[16][260];
  __shared__ float ws[24][260];
  const int tid = threadIdx.x, bid = blockIdx.x;
  const int sg = bid >> 5, cgi = bid & 31, cbase = cgi * 8;
  #pragma unroll
  for (int i = 0; i < 4; ++i){
    int idx4 = tid + i*256, jj = idx4 >> 6, k4 = idx4 & 63;
    *(float4*)&xs[jj][k4*4] = *(const float4*)(updb + ((size_t)(sg + 8*jj))*256 + k4*4);
  }
  #pragma unroll
  for (int i = 0; i < 6; ++i){
    int idx4 = tid + i*256, row = idx4 >> 6, k4 = idx4 & 63;
    int g = row >> 3, rr = row & 7;
    *(float4*)&ws[row][k4*4] =
      *(const float4*)(W_ih + (size_t)g*65536 + ((size_t)(cbase + rr))*256 + k4*4);
  }
  __syncthreads();
  if (tid < 128){
    const int j = tid >> 3, cc = tid & 7, r = sg + 8*j, c = cbase + cc;
    float ir_ = dot256(&ws[cc][0],    &xs[j][0]) + b_ih[c];
    float iz_ = dot256(&ws[8+cc][0],  &xs[j][0]) + b_ih[256 + c];
    float in_ = dot256(&ws[16+cc][0], &xs[j][0]) + b_ih[512 + c];
    float hr_ = ghb[((size_t)0*128 + r)*256 + c];
    float hz_ = ghb[((size_t)1*128 + r)*256 + c];
    float hn_ = ghb[((size_t)2*128 + r)*256 + c];
    float hp  = sin_[(size_t)r*256 + c];
    float rg = 1.f/(1.f + expf(-(ir_ + hr_)));
    float zg = 1.f/(1.f + expf(-(iz_ + hz_)));
    float ng = tanhf(in_ + rg*hn_);
    hbuf[(size_t)r*256 + c] = (1.f - zg)*ng + zg*hp;
    uacc[(size_t)r*256 + c] = 0.f;
  }
  if (cgi == 0 && tid < 16) Zacc[sg + 8*tid] = 0.f;
}

// D4: LN_ff(h) -> W1 -> relu -> hid
__global__ __launch_bounds__(256) void k_ffa(const float* __restrict__ hbuf,
    const float* __restrict__ g_ff, const float* __restrict__ be_ff,
    const float* __restrict__ W1, const float* __restrict__ b1,
    float* __restrict__ hid){
  __shared__ float xs[16][260];
  __shared__ float ws[8][260];
  __shared__ float gA[256], gB[256];
  __shared__ float redA[16][17], redB[16][17];
  __shared__ float musL[16], invsL[16];
  const int tid = threadIdx.x, bid = blockIdx.x;
  const int sg = bid >> 5, cgi = bid & 31, cbase = cgi * 8;
  #pragma unroll
  for (int i = 0; i < 4; ++i){
    int idx4 = tid + i*256, jj = idx4 >> 6, k4 = idx4 & 63;
    *(float4*)&xs[jj][k4*4] = *(const float4*)(hbuf + ((size_t)(sg + 8*jj))*256 + k4*4);
  }
  #pragma unroll
  for (int i = 0; i < 2; ++i){
    int idx4 = tid + i*256, row = idx4 >> 6, k4 = idx4 & 63;
    *(float4*)&ws[row][k4*4] = *(const float4*)(W1 + ((size_t)(cbase + row))*256 + k4*4);
  }
  gA[tid] = g_ff[tid]; gB[tid] = be_ff[tid];
  __syncthreads();
  {
    int jr = tid >> 4, seg = tid & 15;
    float s1 = 0.f, s2 = 0.f;
    #pragma unroll
    for (int i = 0; i < 16; ++i){ float v = xs[jr][seg*16 + i]; s1 += v; s2 += v*v; }
    redA[jr][seg] = s1; redB[jr][seg] = s2;
    __syncthreads();
    if (tid < 16){
      float t1 = 0.f, t2 = 0.f;
      #pragma unroll
      for (int p = 0; p < 16; ++p){ t1 += redA[tid][p]; t2 += redB[tid][p]; }
      float mu = t1 * (1.f/256.f);
      float var = t2 * (1.f/256.f) - mu*mu;
      musL[tid] = mu; invsL[tid] = rsqrtf(var + LN_EPS);
    }
    __syncthreads();
    float mu = musL[jr], inv = invsL[jr];
    #pragma unroll
    for (int i = 0; i < 16; ++i){
      int k = seg*16 + i;
      xs[jr][k] = (xs[jr][k] - mu)*inv*gA[k] + gB[k];
    }
  }
  __syncthreads();
  if (tid < 128){
    const int j = tid >> 3, cc = tid & 7, r = sg + 8*j, c = cbase + cc;
    hid[(size_t)r*256 + c] = fmaxf(dot256(&ws[cc][0], &xs[j][0]) + b1[c], 0.f);
  }
}

// D5: sout = hbuf + hid@W2^T + b2  (+ out_slots on last iter)
__global__ __launch_bounds__(256) void k_ffb(const float* __restrict__ hid,
    const float* __restrict__ hbuf, const float* __restrict__ W2,
    const float* __restrict__ b2, float* __restrict__ sout,
    float* __restrict__ out_slots, int last){
  __shared__ float xs[16][260];
  __shared__ float ws[8][260];
  const int tid = threadIdx.x, bid = blockIdx.x;
  const int sg = bid >> 5, cgi = bid & 31, cbase = cgi * 8;
  #pragma unroll
  for (int i = 0; i < 4; ++i){
    int idx4 = tid + i*256, jj = idx4 >> 6, k4 = idx4 & 63;
    *(float4*)&xs[jj][k4*4] = *(const float4*)(hid + ((size_t)(sg + 8*jj))*256 + k4*4);
  }
  #pragma unroll
  for (int i = 0; i < 2; ++i){
    int idx4 = tid + i*256, row = idx4 >> 6, k4 = idx4 & 63;
    *(float4*)&ws[row][k4*4] = *(const float4*)(W2 + ((size_t)(cbase + row))*256 + k4*4);
  }
  __syncthreads();
  if (tid < 128){
    const int j = tid >> 3, cc = tid & 7, r = sg + 8*j, c = cbase + cc;
    float out = hbuf[(size_t)r*256 + c] + dot256(&ws[cc][0], &xs[j][0]) + b2[c];
    sout[(size_t)r*256 + c] = out;
    if (last) out_slots[(size_t)r*256 + c] = out;
  }
}

// D6: LN_s(sout) -> Wq -> qbuf ; zero gqbq
__global__ __launch_bounds__(256) void k_lnq(const float* __restrict__ sl,
    const float* __restrict__ g_s, const float* __restrict__ be_s,
    const float* __restrict__ Wq, float* __restrict__ qbuf,
    float* __restrict__ gqbq){
  __shared__ float xs[16][260];
  __shared__ float ws[8][260];
  __shared__ float gA[256], gB[256];
  __shared__ float redA[16][17], redB[16][17];
  __shared__ float musL[16], invsL[16];
  const int tid = threadIdx.x, bid = blockIdx.x;
  const int sg = bid >> 5, cgi = bid & 31, cbase = cgi * 8;
  #pragma unroll
  for (int i = 0; i < 4; ++i){
    int idx4 = tid + i*256, jj = idx4 >> 6, k4 = idx4 & 63;
    *(float4*)&xs[jj][k4*4] = *(const float4*)(sl + ((size_t)(sg + 8*jj))*256 + k4*4);
  }
  #pragma unroll
  for (int i = 0; i < 2; ++i){
    int idx4 = tid + i*256, row = idx4 >> 6, k4 = idx4 & 63;
    *(float4*)&ws[row][k4*4] = *(const float4*)(Wq + ((size_t)(cbase + row))*256 + k4*4);
  }
  gA[tid] = g_s[tid]; gB[tid] = be_s[tid];
  __syncthreads();
  {
    int jr = tid >> 4, seg = tid & 15;
    float s1 = 0.f, s2 = 0.f;
    #pragma unroll
    for (int i = 0; i < 16; ++i){ float v = xs[jr][seg*16 + i]; s1 += v; s2 += v*v; }
    redA[jr][seg] = s1; redB[jr][seg] = s2;
    __syncthreads();
    if (tid < 16){
      float t1 = 0.f, t2 = 0.f;
      #pragma unroll
      for (int p = 0; p < 16; ++p){ t1 += redA[tid][p]; t2 += redB[tid][p]; }
      float mu = t1 * (1.f/256.f);
      float var = t2 * (1.f/256.f) - mu*mu;
      musL[tid] = mu; invsL[tid] = rsqrtf(var + LN_EPS);
    }
    __syncthreads();
    float mu = musL[jr], inv = invsL[jr];
    #pragma unroll
    for (int i = 0; i < 16; ++i){
      int k = seg*16 + i;
      xs[jr][k] = (xs[jr][k] - mu)*inv*gA[k] + gB[k];
    }
  }
  __syncthreads();
  if (tid < 128){
    const int j = tid >> 3, cc = tid & 7, r = sg + 8*j, c = cbase + cc;
    qbuf[(size_t)r*256 + c] = dot256(&ws[cc][0], &xs[j][0]);
  }
  if (cgi == 0 && tid < 32)
    gqbq[(sg + 8*(tid>>1))*2 + (tid&1)] = 0.f;
}

// D7: qk = q@Wk[sg] ; qg ; Gq/Bq atomics
__global__ __launch_bounds__(256) void k_qk(const float* __restrict__ qbuf,
    const float* __restrict__ Wk,
    const float* __restrict__ g_in, const float* __restrict__ be_in,
    float* __restrict__ qg, float* __restrict__ gqbq){
  __shared__ float xs[16][260];
  __shared__ float ws[8][260];
  const int tid = threadIdx.x, bid = blockIdx.x;
  const int sg = bid >> 5, cgi = bid & 31, cbase = cgi * 8;
  #pragma unroll
  for (int i = 0; i < 4; ++i){
    int idx4 = tid + i*256, jj = idx4 >> 6, k4 = idx4 & 63;
    *(float4*)&xs[jj][k4*4] = *(const float4*)(qbuf + ((size_t)(sg + 8*jj))*256 + k4*4);
  }
  #pragma unroll
  for (int i = 0; i < 8; ++i){     // gather 8 columns of Wk[sg]
    int idx = tid + i*256;
    int cl = idx & 7, e = idx >> 3;
    ws[cl][e] = Wk[(size_t)sg*65536 + (size_t)e*256 + cbase + cl];
  }
  __syncthreads();
  if (tid < 128){
    const int j = tid >> 3, cc = tid & 7, r = sg + 8*j, c = cbase + cc;
    float qk = dot256(&ws[cc][0], &xs[j][0]);
    float qgv = qk * g_in[c] * SCALE;
    float bqv = qk * be_in[c] * SCALE;
    qg[(size_t)r*256 + c] = qgv;
    float vq = qgv, vb = bqv;
    #pragma unroll
    for (int o = 1; o <= 4; o <<= 1){ vq += __shfl_xor(vq,o,64); vb += __shfl_xor(vb,o,64); }
    if (cc == 0){
      atomicAdd(&gqbq[r*2+0], vq);
      atomicAdd(&gqbq[r*2+1], vb);
    }
  }
}

// ---------------- K1: k_main (blocks 0..1023, unchanged) + gh blocks (1024..1791) ------
__global__ __launch_bounds__(256) void k_main_gh(const float* __restrict__ emb,
    const float* __restrict__ qg, const float* __restrict__ gqbq,
    const float* __restrict__ g_in, const float* __restrict__ be_in,
    float* __restrict__ uacc, float* __restrict__ Zacc,
    float* __restrict__ out_attn, int write_attn,
    const float* __restrict__ sin_, const float* __restrict__ W_hh,
    const float* __restrict__ b_hh, float* __restrict__ ghb){
  __shared__ float U[8192];                    // 32 KB union
  __shared__ float aL[512];
  __shared__ float red2[2][8][4];
  __shared__ float Zs[8], A2s[8], GqL[8], BqL[8];

  const int tid = threadIdx.x, lane = tid & 63, wv = tid >> 6;
  const int blk = blockIdx.x;

  if (blk >= 1024){
    // gh block: gh[g][r][cbase..cbase+8) = sin@W_hh[g]^T + b_hh[g]
    float (*xs)[260]  = (float(*)[260])U;
    float (*wsh)[260] = (float(*)[260])(U + 16*260);
    const int idx = blk - 1024;          // 0..767
    const int g = idx >> 8, sub = idx & 255;
    const int sg = sub >> 5, cgi = sub & 31, cbase = cgi * 8;
    #pragma unroll
    for (int i = 0; i < 4; ++i){
      int idx4 = tid + i*256, jj = idx4 >> 6, k4 = idx4 & 63;
      *(float4*)&xs[jj][k4*4] = *(const float4*)(sin_ + ((size_t)(sg + 8*jj))*256 + k4*4);
    }
    #pragma unroll
    for (int i = 0; i < 2; ++i){
      int idx4 = tid + i*256, row = idx4 >> 6, k4 = idx4 & 63;
      *(float4*)&wsh[row][k4*4] =
        *(const float4*)(W_hh + (size_t)g*65536 + ((size_t)(cbase + row))*256 + k4*4);
    }
    __syncthreads();
    if (tid < 128){
      const int j = tid >> 3, cc = tid & 7, r = sg + 8*j, c = cbase + cc;
      ghb[((size_t)g*128 + r)*256 + c] = dot256(&wsh[cc][0], &xs[j][0]) + b_hh[g*256 + c];
    }
    return;
  }

  float* const qgL = U;
  float* const avL = U + 2048;
  float4* const Sp4 = (float4*)U;

  const int b = blk >> 6, tile = blk & 63;
  const int n0 = tile * 64;

  { // stage queries with per-qq rotation so the 8 qq-chunks hit distinct banks
    const float4* src = (const float4*)(qg + (size_t)b * 2048);
    float4* dst = (float4*)qgL;
    #pragma unroll
    for (int k = 0; k < 2; ++k){
      int w = tid + k*256;
      int s = w >> 6, f = w & 63, qq = f >> 3, j = f & 7;
      dst[s*64 + qq*8 + ((j + qq) & 7)] = src[w];
    }
  }
  if (tid < 8){
    GqL[tid] = gqbq[(b*8 + tid)*2 + 0];
    BqL[tid] = gqbq[(b*8 + tid)*2 + 1];
  }
  __syncthreads();

  const int qq = tid & 7;
  float zsum[8], z2sum[8];
  #pragma unroll
  for (int s = 0; s < 8; ++s){ zsum[s] = 0.f; z2sum[s] = 0.f; }

  #pragma unroll
  for (int pass = 0; pass < 2; ++pass){
    const int t = pass*32 + (tid >> 3);
    const float4* xrow = (const float4*)(emb + ((size_t)(b*4096 + n0 + t))*256 + qq*32);
    float4 xv4[8];
    #pragma unroll
    for (int j = 0; j < 8; ++j) xv4[j] = xrow[j];
    float s1 = 0.f, s2 = 0.f, acc[8];
    #pragma unroll
    for (int s = 0; s < 8; ++s) acc[s] = 0.f;
    #pragma unroll
    for (int j = 0; j < 8; ++j){
      float4 u = xv4[j];
      s1 += (u.x+u.y)+(u.z+u.w);
      s2 += u.x*u.x+u.y*u.y+u.z*u.z+u.w*u.w;
      const float* qb = qgL + qq*32 + ((j + qq) & 7)*4;
      #pragma unroll
      for (int s = 0; s < 8; ++s){
        float4 q0 = *(const float4*)(qb + s*256);
        acc[s] += u.x*q0.x + u.y*q0.y + u.z*q0.z + u.w*q0.w;
      }
    }
    #pragma unroll
    for (int o = 1; o <= 4; o <<= 1){
      s1 += __shfl_xor(s1,o,64); s2 += __shfl_xor(s2,o,64);
      #pragma unroll
      for (int s = 0; s < 8; ++s) acc[s] += __shfl_xor(acc[s],o,64);
    }
    float mu = s1 * (1.f/256.f);
    float var = s2 * (1.f/256.f) - mu*mu;
    float inv = rsqrtf(var + LN_EPS);
    float dv[8], mx = -1e30f;
    #pragma unroll
    for (int s = 0; s < 8; ++s){
      dv[s] = inv * (acc[s] - mu * GqL[s]) + BqL[s];
      mx = fmaxf(mx, dv[s]);
    }
    float den = 0.f;
    #pragma unroll
    for (int s = 0; s < 8; ++s){ dv[s] = expf(dv[s] - mx); den += dv[s]; }
    float rden = 1.f / den;
    #pragma unroll
    for (int s = 0; s < 8; ++s){
      float at = dv[s] * rden;
      float av = at * inv;
      if (qq == 0){ avL[s*64 + t] = at; aL[s*64 + t] = av; }
      zsum[s] += at;
      z2sum[s] += av * mu;
    }
  }
  #pragma unroll
  for (int s = 0; s < 8; ++s){
    #pragma unroll
    for (int o = 32; o; o >>= 1){
      zsum[s] += __shfl_xor(zsum[s], o, 64);
      z2sum[s] += __shfl_xor(z2sum[s], o, 64);
    }
  }
  if (lane == 0){
    #pragma unroll
    for (int s = 0; s < 8; ++s){ red2[0][s][wv] = zsum[s]*0.125f; red2[1][s][wv] = z2sum[s]*0.125f; }
  }
  __syncthreads();
  if (tid < 8){
    Zs[tid]  = red2[0][tid][0]+red2[0][tid][1]+red2[0][tid][2]+red2[0][tid][3];
    A2s[tid] = red2[1][tid][0]+red2[1][tid][1]+red2[1][tid][2]+red2[1][tid][3];
  }
  if (write_attn){
    int s = tid >> 5, tk = tid & 31;
    #pragma unroll
    for (int p = 0; p < 2; ++p)
      out_attn[((size_t)(b*8 + s))*4096 + n0 + p*32 + tk] = avL[s*64 + p*32 + tk];
  }
  __syncthreads();
  {
    const int r4 = tid >> 6, cq = tid & 63;
    float4 S1[8];
    #pragma unroll
    for (int s = 0; s < 8; ++s) S1[s] = make_float4(0.f,0.f,0.f,0.f);
    const float4* xbase = (const float4*)(emb + ((size_t)(b*4096 + n0))*256) + cq;
    #pragma unroll 4
    for (int i = 0; i < 16; ++i){
      int t = r4 + i*4;
      float4 x4 = xbase[t*64];
      #pragma unroll
      for (int s = 0; s < 8; ++s){
        float a = aL[s*64 + t];
        S1[s].x += a*x4.x; S1[s].y += a*x4.y; S1[s].z += a*x4.z; S1[s].w += a*x4.w;
      }
    }
    #pragma unroll
    for (int s = 0; s < 8; ++s) Sp4[(r4*8 + s)*64 + cq] = S1[s];
  }
  __syncthreads();
  {
    const int c = tid;
    const float* Sp = (const float*)Sp4;
    float gc = g_in[c], bc = be_in[c];
    float* dst = uacc + ((size_t)b*8)*256 + c;
    #pragma unroll
    for (int si = 0; si < 8; ++si){
      int s = (si + blk) & 7;
      float v = Sp[(0*8+s)*256 + c] + Sp[(1*8+s)*256 + c]
              + Sp[(2*8+s)*256 + c] + Sp[(3*8+s)*256 + c];
      atomicAdd(&dst[s*256], gc * (v - A2s[s]) + bc * Zs[s]);
    }
    if (tid < 8) atomicAdd(&Zacc[b*8 + tid], Zs[tid]);
  }
}

extern "C" void kernel_launch(void* const* d_in, const int* in_sizes, int n_in,
                              void* d_out, int out_size, void* d_ws, size_t ws_size,
                              hipStream_t stream){
  const float* emb   = (const float*)d_in[0];
  const float* noise = (const float*)d_in[1];
  const float* smu   = (const float*)d_in[2];
  const float* slsig = (const float*)d_in[3];
  const float* Wk    = (const float*)d_in[4];
  const float* Wq    = (const float*)d_in[5];
  const float* Wv    = (const float*)d_in[6];
  const float* W_ih  = (const float*)d_in[7];
  const float* W_hh  = (const float*)d_in[8];
  const float* b_ih  = (const float*)d_in[9];
  const float* b_hh  = (const float*)d_in[10];
  const float* W1    = (const float*)d_in[11];
  const float* b1    = (const float*)d_in[12];
  const float* W2    = (const float*)d_in[13];
  const float* b2    = (const float*)d_in[14];
  const float* g_in  = (const float*)d_in[15];
  const float* be_in = (const float*)d_in[16];
  const float* g_s   = (const float*)d_in[17];
  const float* be_s  = (const float*)d_in[18];
  const float* g_ff  = (const float*)d_in[19];
  const float* be_ff = (const float*)d_in[20];

  float* ws     = (float*)d_ws;
  float* slotsA = ws;                 // 32768
  float* slotsB = ws + 32768;         // 32768
  float* qg     = ws + 65536;         // 32768
  float* gqbq   = ws + 98304;         // 256
  float* uacc   = ws + 98560;         // 32768
  float* Zacc   = ws + 131328;        // 128
  float* updb   = ws + 131456;        // 32768
  float* ghb    = ws + 164224;        // 98304
  float* hbuf   = ws + 262528;        // 32768
  float* hid    = ws + 295296;        // 32768
  float* qbuf   = ws + 328064;        // 32768

  float* out_slots = (float*)d_out;
  float* out_attn  = out_slots + 32768;
  const int has_attn = (out_size >= 32768 + 16*8*4096);

  k_initq<<<dim3(128), dim3(256), 0, stream>>>(noise, smu, slsig, slotsA, uacc, Zacc,
      g_s, be_s, Wq, Wk, g_in, be_in, qg, gqbq);
  for (int it = 0; it < 3; ++it){
    int last = (it == 2);
    float* sin  = (it == 1) ? slotsB : slotsA;
    float* sout = (it == 1) ? slotsA : slotsB;
    k_main_gh<<<dim3(1792), dim3(256), 0, stream>>>(emb, qg, gqbq, g_in, be_in,
        uacc, Zacc, out_attn, last && has_attn, sin, W_hh, b_hh, ghb);
    k_updv<<<dim3(256), dim3(256), 0, stream>>>(uacc, Zacc, Wv, updb);
    k_gru<<<dim3(256), dim3(256), 0, stream>>>(sin, updb, ghb, W_ih, b_ih,
        hbuf, uacc, Zacc);
    k_ffa<<<dim3(256), dim3(256), 0, stream>>>(hbuf, g_ff, be_ff, W1, b1, hid);
    k_ffb<<<dim3(256), dim3(256), 0, stream>>>(hid, hbuf, W2, b2, sout, out_slots, last);
    if (!last){
      k_lnq<<<dim3(256), dim3(256), 0, stream>>>(sout, g_s, be_s, Wq, qbuf, gqbq);
      k_qk<<<dim3(256), dim3(256), 0, stream>>>(qbuf, Wk, g_in, be_in, qg, gqbq);
    }
  }
}